// Round 13
// baseline (637.861 us; speedup 1.0000x reference)
//
#include <hip/hip_runtime.h>
#include <hip/hip_bf16.h>

// Round 13: (1) quant VPT=4 (each codebook ds_read_b128 now feeds 4 vectors:
// LDS-pipe floor halves; r12 measured 0 bank conflicts, keep skew+8-way split,
// same fmaf order & (d,j) first-min). (2) full-batch z in d_out scratch
// (z = 4,194,304 floats fits d_out[0..); out/zq_p written only afterwards)
// -> no CS chunking: 25 dispatches -> 16, quant grid 1024 (4 blocks/CU).
// Outputs (f32): out[1048576] | loss[1] | zq_p[4194304].

__device__ __forceinline__ float silu_rx(float x){ return x / (1.f + expf(-x)); }
__device__ __forceinline__ float b2f_rx(__hip_bfloat16 v){ return __bfloat162float(v); }
__device__ __forceinline__ float ldv_rx(const void* p, int i, int f32m){
  if (f32m) return ((const float*)p)[i];
  return b2f_rx(((const __hip_bfloat16*)p)[i]);
}

// ---------------- workspace layout (float offsets), 9.57 MB ----------------
#define FLAGS_OFF 0
#define LOSS_OFF  4
#define STATS_OFF 8
#define CB32_OFF  128        // 1024x32 f32
#define CBN_OFF   32896      // 1024
#define IDXP_OFF  33984      // 131072 int
#define IDXN_OFF  165056     // 131072 int
#define R2_OFF    296192     // lnp -> hcat_p accum (524288)
#define R3_OFF    820480     // lnn -> hcat_n accum (524288)
#define R1_OFF    1344768    // h (1048576)

// ---------------- input dtype probe + zero accumulators ----------------
__global__ __launch_bounds__(256) void detect_rx(const void* cbv, float* flags, float* lossacc){
  __shared__ int bad;
  if (threadIdx.x == 0) bad = 0;
  __syncthreads();
  const unsigned short* u = (const unsigned short*)cbv;
  int local = 0;
  for (int i = threadIdx.x; i < 32768; i += 256){
    unsigned e = (u[i] >> 7) & 0xFF;
    if (e >= 126) local = 1;
  }
  if (local) bad = 1;
  __syncthreads();
  if (threadIdx.x == 0){
    flags[0] = bad ? 1.f : 0.f;   // 1.0 => inputs are f32
    lossacc[0] = 0.f; lossacc[1] = 0.f;
  }
}

// ---------------- codebook -> f32 + |c|^2 ----------------
__global__ __launch_bounds__(256) void cbprep_rx(const void* cbv, const float* flags,
                                                 float* cb32, float* cbn){
  const int f32m = (flags[0] != 0.f);
  int j = blockIdx.x * 256 + threadIdx.x;
  if (j < 1024){
    float s = 0.f;
    for (int e = 0; e < 32; ++e){
      float v = ldv_rx(cbv, j*32 + e, f32m);
      cb32[j*32 + e] = v;
      s += v*v;
    }
    cbn[j] = s;
  }
}

// ---------------- gemm2 (r11/r12, verified): 32px x 64out tiles ----------------
template<int KCH, int INMODE, bool OUTSILU, bool ATOMIC, int LEVELS>
__global__ __launch_bounds__(256) void gemm2_rx(
    const float* __restrict__ inF, const float* __restrict__ inF2,
    const void* __restrict__ inV,
    const void* __restrict__ W, const void* __restrict__ biasO,
    const void* __restrict__ sbA, const void* __restrict__ sbB,
    const int* __restrict__ idxin, const float* __restrict__ cb32,
    float* __restrict__ outF, const float* __restrict__ flags,
    int KDIM, int OUTC)
{
  __shared__ float As[32][32];
  __shared__ float Bs[32][68];
  __shared__ int   IdxS[32][32];

  const int f32m = (flags[0] != 0.f);
  const int t  = threadIdx.x;
  const int q0 = blockIdx.x << 5;
  const int b  = q0 >> 8;
  const int p0 = q0 & 255;
  const int o0 = blockIdx.y << 6;
  const int k0base = blockIdx.z * KCH;
  const int tx = t & 15, ty = t >> 4;
  float acc[4][2] = {};

  const int sch = t >> 3, spx = (t & 7) << 2;

  if constexpr (INMODE == 3){
    #pragma unroll
    for (int j = 0; j < 4; ++j){
      const int p = p0 + spx + j;
      if constexpr (LEVELS == 4){
        const int l = sch >> 3, kp = sch & 7;
        IdxS[sch][spx + j] = idxin[b*8192 + (((kp << 8) + p) << 2) + l];
      } else {
        IdxS[sch][spx + j] = idxin[b*8192 + (sch << 8) + p];
      }
    }
    __syncthreads();
  }

  for (int kc = 0; kc < KCH; kc += 32){
    const int k0 = k0base + kc;
    if constexpr (INMODE == 0){
      const float4 v = *reinterpret_cast<const float4*>(
          &inF[((b*KDIM + k0 + sch) << 8) + p0 + spx]);
      *reinterpret_cast<float4*>(&As[sch][spx]) = v;
    } else if constexpr (INMODE == 2){
      if (f32m){
        const float* xf = (const float*)inV;
        float4 v = *reinterpret_cast<const float4*>(&xf[((b*KDIM + k0 + sch) << 8) + p0 + spx]);
        v.x = silu_rx(v.x); v.y = silu_rx(v.y); v.z = silu_rx(v.z); v.w = silu_rx(v.w);
        *reinterpret_cast<float4*>(&As[sch][spx]) = v;
      } else {
        const __hip_bfloat16* xb = (const __hip_bfloat16*)inV;
        const int off = ((b*KDIM + k0 + sch) << 8) + p0 + spx;
        #pragma unroll
        for (int j = 0; j < 4; ++j) As[sch][spx + j] = silu_rx(b2f_rx(xb[off + j]));
      }
    } else if constexpr (INMODE == 3){
      const int e = k0 >> 5;
      #pragma unroll
      for (int j = 0; j < 4; ++j)
        As[sch][spx + j] = cb32[((IdxS[sch][spx + j] & 1023) << 5) + e];
    } else { // INMODE 5
      const float* src = (k0 < 128) ? inF : inF2;
      const void* sb   = (k0 < 128) ? sbA : sbB;
      const int kh = k0 & 127;
      const float bb = ldv_rx(sb, kh + sch, f32m);
      float4 v = *reinterpret_cast<const float4*>(&src[((b*128 + kh + sch) << 8) + p0 + spx]);
      v.x = silu_rx(v.x + bb); v.y = silu_rx(v.y + bb);
      v.z = silu_rx(v.z + bb); v.w = silu_rx(v.w + bb);
      *reinterpret_cast<float4*>(&As[sch][spx]) = v;
    }
    if (f32m){
      const float* Wf = (const float*)W;
      #pragma unroll
      for (int r = 0; r < 8; ++r){
        int ii = t + (r << 8); int oo = ii >> 5, cc = ii & 31;
        Bs[cc][oo] = Wf[(o0 + oo)*KDIM + k0 + cc];
      }
    } else {
      const __hip_bfloat16* Wb = (const __hip_bfloat16*)W;
      #pragma unroll
      for (int r = 0; r < 8; ++r){
        int ii = t + (r << 8); int oo = ii >> 5, cc = ii & 31;
        Bs[cc][oo] = b2f_rx(Wb[(o0 + oo)*KDIM + k0 + cc]);
      }
    }
    __syncthreads();
    #pragma unroll
    for (int kk = 0; kk < 32; ++kk){
      const float2 a = *reinterpret_cast<const float2*>(&As[kk][tx << 1]);
      const float4 w = *reinterpret_cast<const float4*>(&Bs[kk][ty << 2]);
      acc[0][0] += w.x*a.x; acc[0][1] += w.x*a.y;
      acc[1][0] += w.y*a.x; acc[1][1] += w.y*a.y;
      acc[2][0] += w.z*a.x; acc[2][1] += w.z*a.y;
      acc[3][0] += w.w*a.x; acc[3][1] += w.w*a.y;
    }
    __syncthreads();
  }
  #pragma unroll
  for (int i = 0; i < 4; ++i){
    const int o = o0 + (ty << 2) + i;
    const int base = ((b*OUTC + o) << 8) + p0 + (tx << 1);
    if constexpr (ATOMIC){
      atomicAdd(&outF[base + 0], acc[i][0]);
      atomicAdd(&outF[base + 1], acc[i][1]);
    } else {
      const float bb = ldv_rx(biasO, o, f32m);
      float v0 = acc[i][0] + bb, v1 = acc[i][1] + bb;
      if constexpr (OUTSILU){ v0 = silu_rx(v0); v1 = silu_rx(v1); }
      *reinterpret_cast<float2*>(&outF[base]) = make_float2(v0, v1);
    }
  }
}

// ---------------- per-sample LN stats over silu(h_half) ----------------
__global__ __launch_bounds__(256) void stats_rx(const float* __restrict__ h, float* __restrict__ stats){
  const int b = blockIdx.x >> 1, half = blockIdx.x & 1;
  const float* base = h + ((b*256 + half*128) << 8);
  float s = 0.f, s2 = 0.f;
  for (int i = threadIdx.x; i < 32768; i += 256){
    float a = silu_rx(base[i]);
    s += a; s2 += a*a;
  }
  __shared__ float sh[2][256];
  sh[0][threadIdx.x] = s; sh[1][threadIdx.x] = s2;
  __syncthreads();
  for (int st = 128; st > 0; st >>= 1){
    if (threadIdx.x < st){
      sh[0][threadIdx.x] += sh[0][threadIdx.x + st];
      sh[1][threadIdx.x] += sh[1][threadIdx.x + st];
    }
    __syncthreads();
  }
  if (threadIdx.x == 0){
    float mu  = sh[0][0] * (1.f/32768.f);
    float var = sh[1][0] * (1.f/32768.f) - mu*mu;
    stats[half*32 + b]      = mu;
    stats[half*32 + 16 + b] = 1.f / sqrtf(var + 1e-5f);
  }
}

// ---------------- LN apply ----------------
__global__ __launch_bounds__(256) void ln_rx(const float* __restrict__ h,
    const void* lwp, const void* lbp, const void* lwn, const void* lbn,
    const float* __restrict__ stats, const float* __restrict__ flags,
    float* __restrict__ lnp, float* __restrict__ lnn){
  const int f32m = (flags[0] != 0.f);
  int i = blockIdx.x * 256 + threadIdx.x;
  int b = i >> 16, c = (i >> 8) & 255, p = i & 255;
  float a = silu_rx(h[i]);
  if (c < 128){
    float v = (a - stats[b]) * stats[16 + b] * ldv_rx(lwp, (c << 8) + p, f32m) + ldv_rx(lbp, (c << 8) + p, f32m);
    lnp[((b*128 + c) << 8) + p] = v;
  } else {
    int cc = c - 128;
    float v = (a - stats[32 + b]) * stats[48 + b] * ldv_rx(lwn, (cc << 8) + p, f32m) + ldv_rx(lbn, (cc << 8) + p, f32m);
    lnn[((b*128 + cc) << 8) + p] = v;
  }
}

// ---------------- VQ search v4: VPT=4, 8-way split, skewed LDS, full batch ----
// gid over 262144: pt = gid&7, vbase = gid>>3 in [0,32768); vectors
// vid_k = vbase + k*32768 (k=0..3) -> bl_k = bl0 + 4k, same w/p/cbase.
// Part pt scans j = t*256 + pt*32 + i (ascending within part); 8-lane shfl
// combine with (d, j) lexicographic min == np first-argmin.
template<int LEVELS>
__global__ __launch_bounds__(256) void quant_rx(const float* __restrict__ z,
    const float* __restrict__ cb32, const float* __restrict__ cbn,
    int* __restrict__ idxout, float* __restrict__ lossacc){
  __shared__ float4 cbT[2056];     // 2048 + skew holes
  __shared__ float  cbnS[1056];    // 1024 + skew holes
  __shared__ float  red[256];

  const int tid = threadIdx.x;
  const int gid = blockIdx.x * 256 + tid;
  const int pt = gid & 7;
  const int vbase = gid >> 3;

  const int w = vbase & 8191;
  int p, cbase;
  if (LEVELS == 4){
    int l = w & 3, n = w >> 2;
    p = n & 255; cbase = (l << 3) + (n >> 8);
  } else {
    p = w & 255; cbase = w >> 8;
  }

  #pragma unroll
  for (int q = 0; q < 4; ++q){
    const int i = tid + (q << 8);
    cbnS[i + (i >> 5)] = cbn[i];
  }

  int blk[4];
  float4 zv[4][8];
  float zn[4];
  #pragma unroll
  for (int k = 0; k < 4; ++k){
    const int vid = vbase + (k << 15);
    blk[k] = vid >> 13;
    const int zoff = ((blk[k] << 10) + cbase) << 8;
    float zs = 0.f;
    #pragma unroll
    for (int e4 = 0; e4 < 8; ++e4){
      float4 a;
      a.x = z[zoff + (((e4<<2)+0) << 13) + p];
      a.y = z[zoff + (((e4<<2)+1) << 13) + p];
      a.z = z[zoff + (((e4<<2)+2) << 13) + p];
      a.w = z[zoff + (((e4<<2)+3) << 13) + p];
      zv[k][e4] = a;
      zs += a.x*a.x; zs += a.y*a.y; zs += a.z*a.z; zs += a.w*a.w;
    }
    zn[k] = zs;
  }

  float best[4] = {__builtin_inff(), __builtin_inff(), __builtin_inff(), __builtin_inff()};
  int bi[4] = {0, 0, 0, 0};

  const int jl0 = pt << 5;
  for (int t = 0; t < 4; ++t){
    __syncthreads();
    const float4* g4 = reinterpret_cast<const float4*>(cb32) + (t << 11);
    #pragma unroll
    for (int r = 0; r < 8; ++r){
      const int idx = tid + (r << 8);
      cbT[idx + (idx >> 8)] = g4[idx];
    }
    __syncthreads();

    #pragma unroll 2
    for (int i = 0; i < 32; ++i){
      const int jl = jl0 + i;
      const int j  = (t << 8) + jl;
      const float4* c = &cbT[(jl << 3) + (jl >> 5)];
      float dot0 = 0.f, dot1 = 0.f, dot2 = 0.f, dot3 = 0.f;
      #pragma unroll
      for (int e4 = 0; e4 < 8; ++e4){
        const float4 cc = c[e4];
        dot0 = fmaf(zv[0][e4].x, cc.x, dot0); dot1 = fmaf(zv[1][e4].x, cc.x, dot1);
        dot2 = fmaf(zv[2][e4].x, cc.x, dot2); dot3 = fmaf(zv[3][e4].x, cc.x, dot3);
        dot0 = fmaf(zv[0][e4].y, cc.y, dot0); dot1 = fmaf(zv[1][e4].y, cc.y, dot1);
        dot2 = fmaf(zv[2][e4].y, cc.y, dot2); dot3 = fmaf(zv[3][e4].y, cc.y, dot3);
        dot0 = fmaf(zv[0][e4].z, cc.z, dot0); dot1 = fmaf(zv[1][e4].z, cc.z, dot1);
        dot2 = fmaf(zv[2][e4].z, cc.z, dot2); dot3 = fmaf(zv[3][e4].z, cc.z, dot3);
        dot0 = fmaf(zv[0][e4].w, cc.w, dot0); dot1 = fmaf(zv[1][e4].w, cc.w, dot1);
        dot2 = fmaf(zv[2][e4].w, cc.w, dot2); dot3 = fmaf(zv[3][e4].w, cc.w, dot3);
      }
      const float cn = cbnS[j + (j >> 5)];
      const float d0 = (zn[0] - 2.f*dot0) + cn;
      const float d1 = (zn[1] - 2.f*dot1) + cn;
      const float d2 = (zn[2] - 2.f*dot2) + cn;
      const float d3 = (zn[3] - 2.f*dot3) + cn;
      if (d0 < best[0]){ best[0] = d0; bi[0] = j; }
      if (d1 < best[1]){ best[1] = d1; bi[1] = j; }
      if (d2 < best[2]){ best[2] = d2; bi[2] = j; }
      if (d3 < best[3]){ best[3] = d3; bi[3] = j; }
    }
  }

  // combine the 8 parts: lexicographic (d, j) min
  #pragma unroll
  for (int k = 4; k > 0; k >>= 1){
    #pragma unroll
    for (int v = 0; v < 4; ++v){
      float od = __shfl_down(best[v], k); int oj = __shfl_down(bi[v], k);
      if (od < best[v] || (od == best[v] && oj < bi[v])){ best[v] = od; bi[v] = oj; }
    }
  }
  if (pt == 0){
    #pragma unroll
    for (int v = 0; v < 4; ++v) idxout[blk[v]*8192 + w] = bi[v];
  }
  red[tid] = (pt == 0) ? (best[0] + best[1] + best[2] + best[3]) : 0.f;
  __syncthreads();
  for (int st = 128; st > 0; st >>= 1){
    if (tid < st) red[tid] += red[tid + st];
    __syncthreads();
  }
  if (tid == 0) atomicAdd(lossacc, red[0]);
}

// ---------------- zq_p output (f32) ----------------
__global__ __launch_bounds__(256) void zqout_rx(const int* __restrict__ idxp,
    const float* __restrict__ cb32, float* __restrict__ out){
  int t = blockIdx.x * 256 + threadIdx.x;
  int l = t & 3, n = (t >> 2) & 2047, e = (t >> 13) & 31, b = t >> 18;
  int id = idxp[b*8192 + (n << 2) + l];
  out[t] = cb32[((id & 1023) << 5) + e];
}

// ---------------- zero hcat accum ----------------
__global__ __launch_bounds__(256) void zero_rx(float* __restrict__ p){
  p[blockIdx.x * 256 + threadIdx.x] = 0.f;
}

// ---------------- loss finalize ----------------
__global__ void loss_rx(const float* __restrict__ lossacc, float* __restrict__ out){
  if (threadIdx.x == 0 && blockIdx.x == 0)
    out[0] = 1.25f * (lossacc[0] + lossacc[1]) * (1.f/4194304.f);
}

extern "C" void kernel_launch(void* const* d_in, const int* in_sizes, int n_in,
                              void* d_out, int out_size, void* d_ws, size_t ws_size,
                              hipStream_t stream){
  (void)in_sizes; (void)n_in; (void)out_size; (void)ws_size;
  const void* x   = d_in[0];
  const void* ciw = d_in[1];
  const void* cib = d_in[2];
  const void* lwp = d_in[3];
  const void* lbp = d_in[4];
  const void* wpi = d_in[5];
  const void* bpi = d_in[6];
  const void* wpo = d_in[7];
  const void* bpo = d_in[8];
  const void* lwn = d_in[9];
  const void* lbn = d_in[10];
  const void* wni = d_in[11];
  const void* bni = d_in[12];
  const void* wno = d_in[13];
  const void* bno = d_in[14];
  const void* cbk = d_in[15];
  const void* cow = d_in[16];
  const void* cob = d_in[17];

  float* ws    = (float*)d_ws;
  float* flags = ws + FLAGS_OFF;
  float* loss  = ws + LOSS_OFF;
  float* stats = ws + STATS_OFF;
  float* cb32  = ws + CB32_OFF;
  float* cbn   = ws + CBN_OFF;
  int*   idxp  = (int*)(ws + IDXP_OFF);
  int*   idxn  = (int*)(ws + IDXN_OFF);
  float* R2    = ws + R2_OFF;
  float* R3    = ws + R3_OFF;
  float* R1    = ws + R1_OFF;

  float* outO = (float*)d_out;
  float* outL = outO + 1048576;
  float* outZ = outO + 1048577;
  float* zbuf = outO;                 // full z scratch: d_out[0 .. 4194304)
                                      // (out/loss/zq_p all written AFTER z dies)

  detect_rx<<<1, 256, 0, stream>>>(cbk, flags, loss);
  cbprep_rx<<<4, 256, 0, stream>>>(cbk, flags, cb32, cbn);
  // h = conv_in(silu(x)) -> R1
  gemm2_rx<256,2,false,false,0><<<dim3(128,4), 256, 0, stream>>>(
      nullptr, nullptr, x, ciw, cib, nullptr, nullptr, nullptr, nullptr,
      R1, flags, 256, 256);
  stats_rx<<<32, 256, 0, stream>>>(R1, stats);
  ln_rx<<<4096, 256, 0, stream>>>(R1, lwp, lbp, lwn, lbn, stats, flags, R2, R3);
  // phylo: full-batch z (R2 -> zbuf), quantize
  gemm2_rx<128,0,true,false,0><<<dim3(128,16), 256, 0, stream>>>(
      R2, nullptr, nullptr, wpi, bpi, nullptr, nullptr, nullptr, nullptr,
      zbuf, flags, 128, 1024);
  quant_rx<4><<<1024, 256, 0, stream>>>(zbuf, cb32, cbn, idxp, loss + 0);
  // non-phylo: reuse zbuf
  gemm2_rx<128,0,true,false,0><<<dim3(128,16), 256, 0, stream>>>(
      R3, nullptr, nullptr, wni, bni, nullptr, nullptr, nullptr, nullptr,
      zbuf, flags, 128, 1024);
  quant_rx<1><<<1024, 256, 0, stream>>>(zbuf, cb32, cbn, idxn, loss + 1);
  // zq_p output (z scratch dead from here)
  zqout_rx<<<16384, 256, 0, stream>>>(idxp, cb32, outZ);
  // hcat accum := 0
  zero_rx<<<4096, 256, 0, stream>>>(R2);
  // hout_p / hout_n: fused gather + split-K x4, atomic accum
  gemm2_rx<256,3,false,true,4><<<dim3(128,2,4), 256, 0, stream>>>(
      nullptr, nullptr, nullptr, wpo, nullptr, nullptr, nullptr, idxp, cb32,
      R2, flags, 1024, 128);
  gemm2_rx<256,3,false,true,1><<<dim3(128,2,4), 256, 0, stream>>>(
      nullptr, nullptr, nullptr, wno, nullptr, nullptr, nullptr, idxn, cb32,
      R3, flags, 1024, 128);
  // out = conv_out(silu(hcat + hout_bias))
  gemm2_rx<256,5,false,false,0><<<dim3(128,4), 256, 0, stream>>>(
      R2, R3, nullptr, cow, cob, bpo, bno, nullptr, nullptr,
      outO, flags, 256, 256);
  loss_rx<<<1, 64, 0, stream>>>(loss, outL);
}